// Round 2
// baseline (248.604 us; speedup 1.0000x reference)
//
#include <hip/hip_runtime.h>
#include <hip/hip_bf16.h>

#define U_DIM 1024
#define H_DIM 4096
#define N_DIM 8192   // 2H
#define K_DIM 4096   // = H

#define BM 128
#define BN 128
#define BK 32

typedef __attribute__((ext_vector_type(8))) short bf16x8;
typedef __attribute__((ext_vector_type(4))) float f32x4;

__device__ inline unsigned short f2bf(float f) {
  union { float f; unsigned u; } a; a.f = f;
  unsigned r = a.u + 0x7fffu + ((a.u >> 16) & 1u);  // RNE
  return (unsigned short)(r >> 16);
}

__device__ inline void gload_lds16(const void* g, void* l) {
  __builtin_amdgcn_global_load_lds(
      (const __attribute__((address_space(1))) unsigned*)(g),
      (__attribute__((address_space(3))) unsigned*)(l), 16, 0, 0);
}

// ---------------- x fp32 -> bf16 ----------------
__global__ __launch_bounds__(256) void convert_x_kernel(
    const float* __restrict__ x, unsigned short* __restrict__ xb) {
  size_t i = (size_t)blockIdx.x * 256 + threadIdx.x;   // each handles 4 elems
  float4 v = ((const float4*)x)[i];
  ushort4 o;
  o.x = f2bf(v.x); o.y = f2bf(v.y); o.z = f2bf(v.z); o.w = f2bf(v.w);
  ((ushort4*)xb)[i] = o;
}

// ---------------- ssm_proj [K][N] fp32 -> Bt [N][K] bf16 ----------------
__global__ __launch_bounds__(256) void transpose_b_kernel(
    const float* __restrict__ B, unsigned short* __restrict__ Bt) {
  __shared__ float tile[64][65];
  const int kt = blockIdx.x % (K_DIM / 64);   // 64 k-tiles
  const int nt = blockIdx.x / (K_DIM / 64);   // 128 n-tiles
  const int k0 = kt * 64, n0 = nt * 64;
  const int tid = threadIdx.x;
  const int cr = tid >> 4;          // 0..15
  const int cc = (tid & 15) * 4;    // 0..60 step 4

#pragma unroll
  for (int it = 0; it < 4; ++it) {
    int r = it * 16 + cr;           // local k row
    float4 v = *(const float4*)(&B[(size_t)(k0 + r) * N_DIM + n0 + cc]);
    tile[r][cc + 0] = v.x; tile[r][cc + 1] = v.y;
    tile[r][cc + 2] = v.z; tile[r][cc + 3] = v.w;
  }
  __syncthreads();
#pragma unroll
  for (int it = 0; it < 4; ++it) {
    int rn = it * 16 + cr;          // local n row
    ushort4 o;
    o.x = f2bf(tile[cc + 0][rn]);
    o.y = f2bf(tile[cc + 1][rn]);
    o.z = f2bf(tile[cc + 2][rn]);
    o.w = f2bf(tile[cc + 3][rn]);
    *(ushort4*)(&Bt[(size_t)(n0 + rn) * K_DIM + k0 + cc]) = o;
  }
}

// ---------------- bf16 MFMA GEMM + fused conv epilogue (+optional state copy) ----
// LDS slot swizzle: LDS[row][slot] holds global k-slot (slot ^ ((row>>1)&3)).
// Staging pre-swizzles the GLOBAL source (global_load_lds dest must be linear,
// rule #21); reads apply the same XOR -> 2 lanes/bank per 16-lane phase (free).
template <bool FUSE>
__global__ __launch_bounds__(256) void gemm_conv_kernel(
    const unsigned short* __restrict__ Abf,   // [U][K] bf16
    const unsigned short* __restrict__ Btbf,  // [N][K] bf16
    const float* __restrict__ conv_states,    // [4][U][N]
    const float* __restrict__ conv_wts,       // [4][N]
    const float* __restrict__ conv_bias,      // [N]
    float* __restrict__ out,                  // [U][N]
    float* __restrict__ ns)                   // [4][U][N] new_states base
{
  __shared__ unsigned short smem[BM * BK + BN * BK];  // 8KB A + 8KB B
  unsigned short* sA = smem;
  unsigned short* sB = smem + BM * BK;

  // bijective XCD swizzle (grid=512, 512%8==0): each XCD gets a contiguous
  // 8x8 (brow x bcol) slab -> shared A + 8 B panels per XCD L2/L3.
  const int bid0 = blockIdx.x;
  const int bid  = (bid0 & 7) * 64 + (bid0 >> 3);
  const int brow = bid & 7;              // 8 row-blocks
  const int bcol = bid >> 3;             // 64 col-blocks
  const int tid  = threadIdx.x;
  const int lane = tid & 63;
  const int wid  = tid >> 6;
  const int wr = wid >> 1, wc = wid & 1;

  f32x4 acc[4][4];
#pragma unroll
  for (int m = 0; m < 4; ++m)
#pragma unroll
    for (int n = 0; n < 4; ++n)
#pragma unroll
      for (int r = 0; r < 4; ++r) acc[m][n][r] = 0.0f;

  const int srow  = lane >> 2;                       // staging row within chunk
  const int sslot = lane & 3;                        // 16B slot
  const int swslot = sslot ^ ((srow >> 1) & 3);      // pre-swizzled global slot
  const int fs    = lane >> 4;                       // k-slot wanted
  const int rdslot = fs ^ ((lane >> 1) & 3);         // swizzled read slot (bits1-2 of lane&15)
  const int fra   = wr * 64 + (lane & 15);           // fragment A row base
  const int frb   = wc * 64 + (lane & 15);           // fragment B row base

  for (int k0 = 0; k0 < K_DIM; k0 += BK) {
    __syncthreads();
#pragma unroll
    for (int i = 0; i < 2; ++i) {
      int rloc = (wid * 2 + i) * 16 + srow;
      const unsigned short* gA =
          Abf + (size_t)(brow * BM + rloc) * K_DIM + k0 + swslot * 8;
      gload_lds16(gA, (char*)sA + (wid * 2 + i) * 1024);
      const unsigned short* gB =
          Btbf + (size_t)(bcol * BN + rloc) * K_DIM + k0 + swslot * 8;
      gload_lds16(gB, (char*)sB + (wid * 2 + i) * 1024);
    }
    __syncthreads();

    bf16x8 af[4], bfr[4];
#pragma unroll
    for (int m = 0; m < 4; ++m)
      af[m] = *(const bf16x8*)((const char*)sA + (fra + m * 16) * (BK * 2) + rdslot * 16);
#pragma unroll
    for (int n = 0; n < 4; ++n)
      bfr[n] = *(const bf16x8*)((const char*)sB + (frb + n * 16) * (BK * 2) + rdslot * 16);

#pragma unroll
    for (int m = 0; m < 4; ++m)
#pragma unroll
      for (int n = 0; n < 4; ++n)
        acc[m][n] = __builtin_amdgcn_mfma_f32_16x16x32_bf16(af[m], bfr[n], acc[m][n], 0, 0, 0);
  }

  // epilogue: out = w0*cs1 + w1*cs2 + w2*cs3 + w3*xp + bias ; ns3 = xp
  // FUSE: also new_states[0..2] = conv_states[1..3] (replaces the d2d memcpy)
  const size_t PL = (size_t)U_DIM * N_DIM;
  const float* cs1 = conv_states + PL;
  const float* cs2 = conv_states + 2 * PL;
  const float* cs3 = conv_states + 3 * PL;
  float* ns0 = ns;
  float* ns1 = ns + PL;
  float* ns2 = ns + 2 * PL;
  float* ns3 = ns + 3 * PL;

#pragma unroll
  for (int n = 0; n < 4; ++n) {
    const int d = bcol * BN + wc * 64 + n * 16 + (lane & 15);
    const float w0 = conv_wts[d];
    const float w1 = conv_wts[N_DIM + d];
    const float w2 = conv_wts[2 * N_DIM + d];
    const float w3 = conv_wts[3 * N_DIM + d];
    const float bs = conv_bias[d];
#pragma unroll
    for (int m = 0; m < 4; ++m) {
#pragma unroll
      for (int r = 0; r < 4; ++r) {
        const int u = brow * BM + wr * 64 + m * 16 + fs * 4 + r;
        const size_t idx = (size_t)u * N_DIM + d;
        const float xpv = acc[m][n][r];
        const float c1 = cs1[idx], c2 = cs2[idx], c3 = cs3[idx];
        out[idx] = w0 * c1 + w1 * c2 + w2 * c3 + w3 * xpv + bs;
        if (FUSE) { ns0[idx] = c1; ns1[idx] = c2; ns2[idx] = c3; }
        ns3[idx] = xpv;
      }
    }
  }
}

extern "C" void kernel_launch(void* const* d_in, const int* in_sizes, int n_in,
                              void* d_out, int out_size, void* d_ws, size_t ws_size,
                              hipStream_t stream) {
  (void)in_sizes; (void)n_in; (void)out_size;
  const float* x           = (const float*)d_in[0];
  const float* ssm_proj    = (const float*)d_in[1];
  const float* conv_states = (const float*)d_in[2];
  const float* conv_wts    = (const float*)d_in[3];
  const float* conv_bias   = (const float*)d_in[4];
  float* outp = (float*)d_out;

  const size_t OUT_ELEMS = (size_t)U_DIM * N_DIM;        // 8M floats
  float* ns = outp + OUT_ELEMS;                          // new_states base

  const size_t BT_BYTES = (size_t)N_DIM * K_DIM * sizeof(unsigned short);  // 64MB
  const size_t XB_BYTES = (size_t)U_DIM * K_DIM * sizeof(unsigned short);  // 8MB

  if (ws_size >= BT_BYTES + XB_BYTES) {
    // scratch in d_ws -> GEMM epilogue can write new_states[0..2] directly
    unsigned short* Btbf = (unsigned short*)d_ws;
    unsigned short* xbf  = (unsigned short*)((char*)d_ws + BT_BYTES);
    convert_x_kernel<<<(U_DIM * H_DIM / 4) / 256, 256, 0, stream>>>(x, xbf);
    transpose_b_kernel<<<(N_DIM / 64) * (K_DIM / 64), 256, 0, stream>>>(ssm_proj, Btbf);
    gemm_conv_kernel<true><<<(U_DIM / BM) * (N_DIM / BN), 256, 0, stream>>>(
        xbf, Btbf, conv_states, conv_wts, conv_bias, outp, ns);
  } else {
    // fallback: scratch inside d_out's new_states[0:2] region, copy after GEMM
    unsigned short* Btbf = (unsigned short*)ns;
    unsigned short* xbf  = (unsigned short*)(ns + 2 * OUT_ELEMS);
    convert_x_kernel<<<(U_DIM * H_DIM / 4) / 256, 256, 0, stream>>>(x, xbf);
    transpose_b_kernel<<<(N_DIM / 64) * (K_DIM / 64), 256, 0, stream>>>(ssm_proj, Btbf);
    gemm_conv_kernel<false><<<(U_DIM / BM) * (N_DIM / BN), 256, 0, stream>>>(
        xbf, Btbf, conv_states, conv_wts, conv_bias, outp, ns);
    hipMemcpyAsync(ns, conv_states + OUT_ELEMS, 3 * OUT_ELEMS * sizeof(float),
                   hipMemcpyDeviceToDevice, stream);
  }
}

// Round 3
// 232.280 us; speedup vs baseline: 1.0703x; 1.0703x over previous
//
#include <hip/hip_runtime.h>
#include <hip/hip_bf16.h>

#define U_DIM 1024
#define H_DIM 4096
#define N_DIM 8192   // 2H
#define K_DIM 4096   // = H

#define BM 128
#define BN 128
#define BK 32
#define NT (K_DIM / BK)   // 128 K-steps

typedef __attribute__((ext_vector_type(8))) short bf16x8;
typedef __attribute__((ext_vector_type(4))) float f32x4;

__device__ inline unsigned short f2bf(float f) {
  union { float f; unsigned u; } a; a.f = f;
  unsigned r = a.u + 0x7fffu + ((a.u >> 16) & 1u);  // RNE
  return (unsigned short)(r >> 16);
}

__device__ inline void gload_lds16(const void* g, void* l) {
  __builtin_amdgcn_global_load_lds(
      (const __attribute__((address_space(1))) unsigned*)(g),
      (__attribute__((address_space(3))) unsigned*)(l), 16, 0, 0);
}

// ---------------- x fp32 -> bf16 ----------------
__global__ __launch_bounds__(256) void convert_x_kernel(
    const float* __restrict__ x, unsigned short* __restrict__ xb) {
  size_t i = (size_t)blockIdx.x * 256 + threadIdx.x;   // each handles 4 elems
  float4 v = ((const float4*)x)[i];
  ushort4 o;
  o.x = f2bf(v.x); o.y = f2bf(v.y); o.z = f2bf(v.z); o.w = f2bf(v.w);
  ((ushort4*)xb)[i] = o;
}

// ---------------- ssm_proj [K][N] fp32 -> Bt [N][K] bf16 ----------------
__global__ __launch_bounds__(256) void transpose_b_kernel(
    const float* __restrict__ B, unsigned short* __restrict__ Bt) {
  __shared__ float tile[64][65];
  const int kt = blockIdx.x % (K_DIM / 64);   // 64 k-tiles
  const int nt = blockIdx.x / (K_DIM / 64);   // 128 n-tiles
  const int k0 = kt * 64, n0 = nt * 64;
  const int tid = threadIdx.x;
  const int cr = tid >> 4;          // 0..15
  const int cc = (tid & 15) * 4;    // 0..60 step 4

#pragma unroll
  for (int it = 0; it < 4; ++it) {
    int r = it * 16 + cr;           // local k row
    float4 v = *(const float4*)(&B[(size_t)(k0 + r) * N_DIM + n0 + cc]);
    tile[r][cc + 0] = v.x; tile[r][cc + 1] = v.y;
    tile[r][cc + 2] = v.z; tile[r][cc + 3] = v.w;
  }
  __syncthreads();
#pragma unroll
  for (int it = 0; it < 4; ++it) {
    int rn = it * 16 + cr;          // local n row
    ushort4 o;
    o.x = f2bf(tile[cc + 0][rn]);
    o.y = f2bf(tile[cc + 1][rn]);
    o.z = f2bf(tile[cc + 2][rn]);
    o.w = f2bf(tile[cc + 3][rn]);
    *(ushort4*)(&Bt[(size_t)(n0 + rn) * K_DIM + k0 + cc]) = o;
  }
}

// ------- bf16 MFMA GEMM, 512 threads, double-buffered LDS 2-phase pipeline -------
// Schedule per K-step: issue next tile's global_load_lds FIRST, then ds_read+MFMA
// on current tile (hides load latency), then one __syncthreads (vmcnt drain lands
// after the compute phase). LDS slot swizzle as round 2 (0 bank conflicts).
template <bool FUSE>
__global__ __launch_bounds__(512, 4) void gemm_conv_kernel(
    const unsigned short* __restrict__ Abf,   // [U][K] bf16
    const unsigned short* __restrict__ Btbf,  // [N][K] bf16
    const float* __restrict__ conv_states,    // [4][U][N]
    const float* __restrict__ conv_wts,       // [4][N]
    const float* __restrict__ conv_bias,      // [N]
    float* __restrict__ out,                  // [U][N]
    float* __restrict__ ns)                   // [4][U][N] new_states base
{
  // 2 buffers x (A 8KB + B 8KB) = 32KB
  __shared__ unsigned short smem[2 * 2 * BM * BK];

  const int bid0 = blockIdx.x;
  const int bid  = (bid0 & 7) * 64 + (bid0 >> 3);  // bijective XCD swizzle (512%8==0)
  const int brow = bid & 7;              // 8 row-blocks
  const int bcol = bid >> 3;             // 64 col-blocks
  const int tid  = threadIdx.x;
  const int lane = tid & 63;
  const int wid  = tid >> 6;             // 0..7
  const int wr = wid >> 2;               // 0..1 -> 64-row group
  const int wc = wid & 3;                // 0..3 -> 32-col group

  f32x4 acc[4][2];
#pragma unroll
  for (int m = 0; m < 4; ++m)
#pragma unroll
    for (int n = 0; n < 2; ++n)
#pragma unroll
      for (int r = 0; r < 4; ++r) acc[m][n][r] = 0.0f;

  // staging: 512 lanes x 16B = 8KB = one full [128][BK] bf16 tile per matrix
  const int srow   = wid * 16 + (lane >> 2);         // 0..127 tile row
  const int sslot  = lane & 3;                       // 16B slot in 64B row
  const int swslot = sslot ^ ((srow >> 1) & 3);      // pre-swizzled global slot
  const int fs     = lane >> 4;                      // wanted k-slot
  const int rdslot = fs ^ ((lane >> 1) & 3);         // swizzled read slot
  const int fra    = wr * 64 + (lane & 15);          // A fragment row base
  const int frb    = wc * 32 + (lane & 15);          // B fragment row base

  const unsigned short* gA0 = Abf  + (size_t)(brow * BM + srow) * K_DIM + swslot * 8;
  const unsigned short* gB0 = Btbf + (size_t)(bcol * BN + srow) * K_DIM + swslot * 8;

  // prologue: stage tile 0 into buf 0
  gload_lds16(gA0, (char*)smem + wid * 1024);
  gload_lds16(gB0, (char*)smem + 8192 + wid * 1024);
  __syncthreads();

  int p = 0;
  for (int t = 0; t < NT; ++t) {
    // issue next tile's loads into buf 1-p (in flight during compute below)
    if (t + 1 < NT) {
      const int k1 = (t + 1) * BK;
      char* dstA = (char*)smem + (1 - p) * 16384 + wid * 1024;
      char* dstB = dstA + 8192;
      gload_lds16(gA0 + k1, dstA);
      gload_lds16(gB0 + k1, dstB);
    }

    const char* sA = (const char*)smem + p * 16384;
    const char* sB = sA + 8192;
    bf16x8 af[4], bfr[2];
#pragma unroll
    for (int m = 0; m < 4; ++m)
      af[m] = *(const bf16x8*)(sA + (fra + m * 16) * (BK * 2) + rdslot * 16);
#pragma unroll
    for (int n = 0; n < 2; ++n)
      bfr[n] = *(const bf16x8*)(sB + (frb + n * 16) * (BK * 2) + rdslot * 16);

#pragma unroll
    for (int m = 0; m < 4; ++m)
#pragma unroll
      for (int n = 0; n < 2; ++n)
        acc[m][n] = __builtin_amdgcn_mfma_f32_16x16x32_bf16(af[m], bfr[n], acc[m][n], 0, 0, 0);

    // single barrier per iter: per-wave vmcnt(0)+lgkmcnt(0) drain happens here,
    // AFTER the compute phase covered the in-flight next-tile loads
    __syncthreads();
    p ^= 1;
  }

  // epilogue: out = w0*cs1 + w1*cs2 + w2*cs3 + w3*xp + bias ; ns3 = xp
  // FUSE: also new_states[0..2] = conv_states[1..3] (replaces the d2d memcpy)
  const size_t PL = (size_t)U_DIM * N_DIM;
  const float* cs1 = conv_states + PL;
  const float* cs2 = conv_states + 2 * PL;
  const float* cs3 = conv_states + 3 * PL;
  float* ns0 = ns;
  float* ns1 = ns + PL;
  float* ns2 = ns + 2 * PL;
  float* ns3 = ns + 3 * PL;

#pragma unroll
  for (int n = 0; n < 2; ++n) {
    const int d = bcol * BN + wc * 32 + n * 16 + (lane & 15);
    const float w0 = conv_wts[d];
    const float w1 = conv_wts[N_DIM + d];
    const float w2 = conv_wts[2 * N_DIM + d];
    const float w3 = conv_wts[3 * N_DIM + d];
    const float bs = conv_bias[d];
#pragma unroll
    for (int m = 0; m < 4; ++m) {
#pragma unroll
      for (int r = 0; r < 4; ++r) {
        const int u = brow * BM + wr * 64 + m * 16 + fs * 4 + r;
        const size_t idx = (size_t)u * N_DIM + d;
        const float xpv = acc[m][n][r];
        const float c1 = cs1[idx], c2 = cs2[idx], c3 = cs3[idx];
        out[idx] = w0 * c1 + w1 * c2 + w2 * c3 + w3 * xpv + bs;
        if (FUSE) { ns0[idx] = c1; ns1[idx] = c2; ns2[idx] = c3; }
        ns3[idx] = xpv;
      }
    }
  }
}

extern "C" void kernel_launch(void* const* d_in, const int* in_sizes, int n_in,
                              void* d_out, int out_size, void* d_ws, size_t ws_size,
                              hipStream_t stream) {
  (void)in_sizes; (void)n_in; (void)out_size;
  const float* x           = (const float*)d_in[0];
  const float* ssm_proj    = (const float*)d_in[1];
  const float* conv_states = (const float*)d_in[2];
  const float* conv_wts    = (const float*)d_in[3];
  const float* conv_bias   = (const float*)d_in[4];
  float* outp = (float*)d_out;

  const size_t OUT_ELEMS = (size_t)U_DIM * N_DIM;        // 8M floats
  float* ns = outp + OUT_ELEMS;                          // new_states base

  const size_t BT_BYTES = (size_t)N_DIM * K_DIM * sizeof(unsigned short);  // 64MB
  const size_t XB_BYTES = (size_t)U_DIM * K_DIM * sizeof(unsigned short);  // 8MB

  if (ws_size >= BT_BYTES + XB_BYTES) {
    // scratch in d_ws -> GEMM epilogue writes new_states[0..2] directly
    unsigned short* Btbf = (unsigned short*)d_ws;
    unsigned short* xbf  = (unsigned short*)((char*)d_ws + BT_BYTES);
    convert_x_kernel<<<(U_DIM * H_DIM / 4) / 256, 256, 0, stream>>>(x, xbf);
    transpose_b_kernel<<<(N_DIM / 64) * (K_DIM / 64), 256, 0, stream>>>(ssm_proj, Btbf);
    gemm_conv_kernel<true><<<(U_DIM / BM) * (N_DIM / BN), 512, 0, stream>>>(
        xbf, Btbf, conv_states, conv_wts, conv_bias, outp, ns);
  } else {
    // fallback: scratch inside d_out's new_states[0:2] region, copy after GEMM
    unsigned short* Btbf = (unsigned short*)ns;
    unsigned short* xbf  = (unsigned short*)(ns + 2 * OUT_ELEMS);
    convert_x_kernel<<<(U_DIM * H_DIM / 4) / 256, 256, 0, stream>>>(x, xbf);
    transpose_b_kernel<<<(N_DIM / 64) * (K_DIM / 64), 256, 0, stream>>>(ssm_proj, Btbf);
    gemm_conv_kernel<false><<<(U_DIM / BM) * (N_DIM / BN), 512, 0, stream>>>(
        xbf, Btbf, conv_states, conv_wts, conv_bias, outp, ns);
    hipMemcpyAsync(ns, conv_states + OUT_ELEMS, 3 * OUT_ELEMS * sizeof(float),
                   hipMemcpyDeviceToDevice, stream);
  }
}

// Round 4
// 228.190 us; speedup vs baseline: 1.0895x; 1.0179x over previous
//
#include <hip/hip_runtime.h>
#include <hip/hip_bf16.h>

#define U_DIM 1024
#define H_DIM 4096
#define N_DIM 8192   // 2H
#define K_DIM 4096   // = H

#define BM 128
#define BN 128
#define BK 64
#define NT (K_DIM / BK)   // 64 K-steps

typedef __attribute__((ext_vector_type(8))) short bf16x8;
typedef __attribute__((ext_vector_type(4))) float f32x4;

__device__ inline unsigned short f2bf(float f) {
  union { float f; unsigned u; } a; a.f = f;
  unsigned r = a.u + 0x7fffu + ((a.u >> 16) & 1u);  // RNE
  return (unsigned short)(r >> 16);
}

__device__ inline void gload_lds16(const void* g, void* l) {
  __builtin_amdgcn_global_load_lds(
      (const __attribute__((address_space(1))) unsigned*)(g),
      (__attribute__((address_space(3))) unsigned*)(l), 16, 0, 0);
}

// ---------------- x fp32 -> bf16 ----------------
__global__ __launch_bounds__(256) void convert_x_kernel(
    const float* __restrict__ x, unsigned short* __restrict__ xb) {
  size_t i = (size_t)blockIdx.x * 256 + threadIdx.x;   // each handles 4 elems
  float4 v = ((const float4*)x)[i];
  ushort4 o;
  o.x = f2bf(v.x); o.y = f2bf(v.y); o.z = f2bf(v.z); o.w = f2bf(v.w);
  ((ushort4*)xb)[i] = o;
}

// ------- bf16 MFMA GEMM, BK=64, dbuf, B staged DIRECTLY from fp32 [K][N] -------
// A: bf16 [U][K], staged via global_load_lds (pre-swizzled source, linear dest).
// B: fp32 [K][N], reg-staged: 16 coalesced dword loads issued BEFORE the MFMA
//    phase (T14 issue-early/write-late), cvt->ds_write_b128 after, into LDS
//    layout Bt[n][k] bf16 with slot^(row&7) swizzle (2 lanes/bank = free).
template <bool FUSE>
__global__ __launch_bounds__(512, 4) void gemm_conv_kernel(
    const unsigned short* __restrict__ Abf,   // [U][K] bf16
    const float* __restrict__ Bmat,           // [K][N] fp32 (ssm_proj)
    const float* __restrict__ conv_states,    // [4][U][N]
    const float* __restrict__ conv_wts,       // [4][N]
    const float* __restrict__ conv_bias,      // [N]
    float* __restrict__ out,                  // [U][N]
    float* __restrict__ ns)                   // [4][U][N] new_states base
{
  // 2 buffers x (A 16KB + B 16KB) = 64KB -> 2 blocks/CU
  __shared__ char smem[2 * 32768];

  const int bid0 = blockIdx.x;
  const int bid  = (bid0 & 7) * 64 + (bid0 >> 3);  // bijective XCD swizzle (512%8==0)
  const int brow = bid & 7;              // 8 row-blocks
  const int bcol = bid >> 3;             // 64 col-blocks
  const int tid  = threadIdx.x;
  const int lane = tid & 63;
  const int wid  = tid >> 6;             // 0..7
  const int wr = wid >> 2;               // 0..1 -> 64-row group
  const int wc = wid & 3;                // 0..3 -> 32-col group

  f32x4 acc[4][2];
#pragma unroll
  for (int m = 0; m < 4; ++m)
#pragma unroll
    for (int n = 0; n < 2; ++n)
#pragma unroll
      for (int r = 0; r < 4; ++r) acc[m][n][r] = 0.0f;

  // ---- A staging: 2 x global_load_lds of 8KB (512 lanes x 16B), rows 0..63 / 64..127
  const int arow = tid >> 3;                       // 0..63 (issue 0), +64 (issue 1)
  const int aswz = (tid & 7) ^ (arow & 7);         // pre-swizzled global k-slot
  const unsigned short* gA  = Abf + (size_t)(brow * BM + arow) * K_DIM + aswz * 8;
  const unsigned short* gA1 = gA + (size_t)64 * K_DIM;

  // ---- B staging: thread covers n=bn, k = bkg*16 .. +16 of the [64][128] tile
  const int bn  = tid & 127;                       // 0..127 (n within tile)
  const int bkg = tid >> 7;                        // 0..3   (16-k group)
  const float* gB = Bmat + (size_t)(bkg * 16) * N_DIM + (size_t)bcol * BN + bn;
  const int bws0 = bn * 128 + (((2 * bkg + 0) ^ (bn & 7)) * 16);  // byte in B half
  const int bws1 = bn * 128 + (((2 * bkg + 1) ^ (bn & 7)) * 16);

  // ---- fragment reads
  const int l15 = lane & 15;
  const int fs  = lane >> 4;             // k-slot within 32-k half
  const int rsw = lane & 7;              // row&7 for read-side swizzle
  const int fra = wr * 64 + l15;         // A fragment row base
  const int frb = wc * 32 + l15;         // B fragment row base

  // ---- prologue: stage tile 0 into buf 0
  gload_lds16(gA,  smem + wid * 1024);
  gload_lds16(gA1, smem + 8192 + wid * 1024);
  {
    float tb[16];
#pragma unroll
    for (int j = 0; j < 16; ++j) tb[j] = gB[(size_t)j * N_DIM];
    union { bf16x8 v; unsigned short u[8]; } w0, w1;
#pragma unroll
    for (int j = 0; j < 8; ++j) { w0.u[j] = f2bf(tb[j]); w1.u[j] = f2bf(tb[j + 8]); }
    *(bf16x8*)(smem + 16384 + bws0) = w0.v;
    *(bf16x8*)(smem + 16384 + bws1) = w1.v;
  }
  __syncthreads();

  int p = 0;
  for (int t = 0; t < NT; ++t) {
    const int q = p ^ 1;
    const bool pf = (t + 1 < NT);
    float tb[16];
    if (pf) {
      // issue next tile's loads FIRST (in flight across the MFMA phase)
      const size_t koff = (size_t)(t + 1) * BK;
      gload_lds16(gA + koff,  smem + q * 32768 + wid * 1024);
      gload_lds16(gA1 + koff, smem + q * 32768 + 8192 + wid * 1024);
      const float* gBt = gB + koff * N_DIM;
#pragma unroll
      for (int j = 0; j < 16; ++j) tb[j] = gBt[(size_t)j * N_DIM];
    }

    // compute on buf p
    const char* sA = smem + p * 32768;
    const char* sB = sA + 16384;
#pragma unroll
    for (int kk = 0; kk < 2; ++kk) {
      const int ks = ((kk * 4 + fs) ^ rsw) * 16;
      bf16x8 af[4], bv[2];
#pragma unroll
      for (int m = 0; m < 4; ++m)
        af[m] = *(const bf16x8*)(sA + (fra + m * 16) * 128 + ks);
#pragma unroll
      for (int n = 0; n < 2; ++n)
        bv[n] = *(const bf16x8*)(sB + (frb + n * 16) * 128 + ks);
#pragma unroll
      for (int m = 0; m < 4; ++m)
#pragma unroll
        for (int n = 0; n < 2; ++n)
          acc[m][n] = __builtin_amdgcn_mfma_f32_16x16x32_bf16(af[m], bv[n], acc[m][n], 0, 0, 0);
    }

    if (pf) {
      // write-late: cvt + ds_write the prefetched B into buf q
      union { bf16x8 v; unsigned short u[8]; } w0, w1;
#pragma unroll
      for (int j = 0; j < 8; ++j) { w0.u[j] = f2bf(tb[j]); w1.u[j] = f2bf(tb[j + 8]); }
      char* dB = smem + q * 32768 + 16384;
      *(bf16x8*)(dB + bws0) = w0.v;
      *(bf16x8*)(dB + bws1) = w1.v;
    }
    __syncthreads();   // drains vmcnt (A DMA) + lgkmcnt (B writes) for buf q
    p ^= 1;
  }

  // epilogue: out = w0*cs1 + w1*cs2 + w2*cs3 + w3*xp + bias ; ns3 = xp
  // FUSE: also new_states[0..2] = conv_states[1..3] (replaces the d2d memcpy)
  const size_t PL = (size_t)U_DIM * N_DIM;
  const float* cs1 = conv_states + PL;
  const float* cs2 = conv_states + 2 * PL;
  const float* cs3 = conv_states + 3 * PL;
  float* ns0 = ns;
  float* ns1 = ns + PL;
  float* ns2 = ns + 2 * PL;
  float* ns3 = ns + 3 * PL;

#pragma unroll
  for (int n = 0; n < 2; ++n) {
    const int d = bcol * BN + wc * 32 + n * 16 + l15;
    const float w0 = conv_wts[d];
    const float w1 = conv_wts[N_DIM + d];
    const float w2 = conv_wts[2 * N_DIM + d];
    const float w3 = conv_wts[3 * N_DIM + d];
    const float bs = conv_bias[d];
#pragma unroll
    for (int m = 0; m < 4; ++m) {
#pragma unroll
      for (int r = 0; r < 4; ++r) {
        const int u = brow * BM + wr * 64 + m * 16 + fs * 4 + r;
        const size_t idx = (size_t)u * N_DIM + d;
        const float xpv = acc[m][n][r];
        const float c1 = cs1[idx], c2 = cs2[idx], c3 = cs3[idx];
        out[idx] = w0 * c1 + w1 * c2 + w2 * c3 + w3 * xpv + bs;
        if (FUSE) { ns0[idx] = c1; ns1[idx] = c2; ns2[idx] = c3; }
        ns3[idx] = xpv;
      }
    }
  }
}

extern "C" void kernel_launch(void* const* d_in, const int* in_sizes, int n_in,
                              void* d_out, int out_size, void* d_ws, size_t ws_size,
                              hipStream_t stream) {
  (void)in_sizes; (void)n_in; (void)out_size;
  const float* x           = (const float*)d_in[0];
  const float* ssm_proj    = (const float*)d_in[1];
  const float* conv_states = (const float*)d_in[2];
  const float* conv_wts    = (const float*)d_in[3];
  const float* conv_bias   = (const float*)d_in[4];
  float* outp = (float*)d_out;

  const size_t OUT_ELEMS = (size_t)U_DIM * N_DIM;        // 8M floats
  float* ns = outp + OUT_ELEMS;                          // new_states base

  const size_t XB_BYTES = (size_t)U_DIM * K_DIM * sizeof(unsigned short);  // 8MB

  if (ws_size >= XB_BYTES) {
    // xbf in d_ws -> GEMM epilogue writes new_states[0..2] directly
    unsigned short* xbf = (unsigned short*)d_ws;
    convert_x_kernel<<<(U_DIM * H_DIM / 4) / 256, 256, 0, stream>>>(x, xbf);
    gemm_conv_kernel<true><<<(U_DIM / BM) * (N_DIM / BN), 512, 0, stream>>>(
        xbf, ssm_proj, conv_states, conv_wts, conv_bias, outp, ns);
  } else {
    // fallback: xbf inside d_out's new_states region, states copied after GEMM
    unsigned short* xbf = (unsigned short*)(ns + 2 * OUT_ELEMS);
    convert_x_kernel<<<(U_DIM * H_DIM / 4) / 256, 256, 0, stream>>>(x, xbf);
    gemm_conv_kernel<false><<<(U_DIM / BM) * (N_DIM / BN), 512, 0, stream>>>(
        xbf, ssm_proj, conv_states, conv_wts, conv_bias, outp, ns);
    hipMemcpyAsync(ns, conv_states + OUT_ELEMS, 3 * OUT_ELEMS * sizeof(float),
                   hipMemcpyDeviceToDevice, stream);
  }
}